// Round 1
// baseline (73.210 us; speedup 1.0000x reference)
//
#include <hip/hip_runtime.h>

#define PAD 4
#define HH 224
#define WW 224
#define CC 3
#define NN 256

__global__ __launch_bounds__(256) void RandomShiftsAug_kernel(
    const float* __restrict__ x, const int* __restrict__ shift,
    float* __restrict__ out) {
    const int W4 = WW / 4;                       // 56 float4 per row
    const int total4 = NN * CC * HH * W4;        // 9,633,792
    int idx = blockIdx.x * blockDim.x + threadIdx.x;
    if (idx >= total4) return;

    int j4   = idx % W4;
    int rest = idx / W4;
    int i    = rest % HH;
    rest    /= HH;
    int c    = rest % CC;
    int n    = rest / CC;

    int sx = shift[n * 2 + 0];
    int sy = shift[n * 2 + 1];

    int si = i + sy - PAD;
    si = si < 0 ? 0 : (si > HH - 1 ? HH - 1 : si);

    const float* src_row = x + ((size_t)(n * CC + c) * HH + si) * WW;

    int c0 = j4 * 4 + sx - PAD;
    float r[4];
#pragma unroll
    for (int k = 0; k < 4; ++k) {
        int col = c0 + k;
        col = col < 0 ? 0 : (col > WW - 1 ? WW - 1 : col);
        r[k] = src_row[col];
    }

    reinterpret_cast<float4*>(out)[idx] = make_float4(r[0], r[1], r[2], r[3]);
}

extern "C" void kernel_launch(void* const* d_in, const int* in_sizes, int n_in,
                              void* d_out, int out_size, void* d_ws, size_t ws_size,
                              hipStream_t stream) {
    const float* x     = (const float*)d_in[0];
    const int*   shift = (const int*)d_in[1];
    float* out = (float*)d_out;

    const int total4 = NN * CC * HH * (WW / 4);
    dim3 block(256);
    dim3 grid((total4 + 255) / 256);
    RandomShiftsAug_kernel<<<grid, block, 0, stream>>>(x, shift, out);
}

// Round 2
// 47.927 us; speedup vs baseline: 1.5275x; 1.5275x over previous
//
#include <hip/hip_runtime.h>

#define PAD 4
#define HH 224
#define WW 224
#define CC 3
#define NN 256

typedef float f4 __attribute__((ext_vector_type(4)));

__global__ __launch_bounds__(256) void RandomShiftsAug_kernel(
    const float* __restrict__ x, const int* __restrict__ shift,
    float* __restrict__ out) {
    const int W4 = WW / 4;                       // 56 float4 per row
    const int total4 = NN * CC * HH * W4;        // 9,633,792
    int idx = blockIdx.x * blockDim.x + threadIdx.x;
    if (idx >= total4) return;

    int j4   = idx % W4;
    int rest = idx / W4;
    int i    = rest % HH;
    rest    /= HH;
    int c    = rest % CC;
    int n    = rest / CC;

    // n (hence sx,sy) is wave-uniform: 37632 float4 per image = 588 full waves
    int sx = shift[n * 2 + 0];
    int sy = shift[n * 2 + 1];

    int si = i + sy - PAD;
    si = si < 0 ? 0 : (si > HH - 1 ? HH - 1 : si);

    const float* src_row = x + ((size_t)(n * CC + c) * HH + si) * WW;

    int c0 = j4 * 4 + sx - PAD;                  // desired first col, in [-4, 224]
    int cb = c0 < 0 ? 0 : (c0 > WW - 4 ? WW - 4 : c0);  // dword-aligned vector base

    // one unaligned (dword-aligned) 16B load; gfx950 global loads need only
    // 4B alignment
    f4 v = *reinterpret_cast<const f4*>(src_row + cb);

    f4 r = v;
    int d = c0 - cb;                             // nonzero only at row edges
    if (d != 0) {
        // r[k] = v[clamp(d+k, 0, 3)] — exec-masked, <=2 lanes/row take this
#pragma unroll
        for (int k = 0; k < 4; ++k) {
            int id = d + k;
            id = id < 0 ? 0 : (id > 3 ? 3 : id);
            float t = v[0];
            t = id >= 1 ? v[1] : t;
            t = id >= 2 ? v[2] : t;
            t = id >= 3 ? v[3] : t;
            r[k] = t;
        }
    }

    __builtin_nontemporal_store(r, reinterpret_cast<f4*>(out) + idx);
}

extern "C" void kernel_launch(void* const* d_in, const int* in_sizes, int n_in,
                              void* d_out, int out_size, void* d_ws, size_t ws_size,
                              hipStream_t stream) {
    const float* x     = (const float*)d_in[0];
    const int*   shift = (const int*)d_in[1];
    float* out = (float*)d_out;

    const int total4 = NN * CC * HH * (WW / 4);
    dim3 block(256);
    dim3 grid((total4 + 255) / 256);
    RandomShiftsAug_kernel<<<grid, block, 0, stream>>>(x, shift, out);
}